// Round 3
// baseline (186.592 us; speedup 1.0000x reference)
//
#include <hip/hip_runtime.h>
#include <math.h>

// Fused single-kernel DSVF biquad IIR (scipy lfilter DF2T), B=512, T=32768.
// One block per row: 512 threads (8 waves), chunk = 64 samples per thread.
// R3 change vs R2: drop the 133 KB LDS row-transpose entirely. Each lane
// loads its OWN chunk directly from global (16 x dwordx4, per-thread
// contiguous 256 B, lane stride 256 B). Every 64-B line is fully consumed
// within 4 adjacent quad-iterations -> same HBM traffic, no transpose.
// LDS drops to the 8 KB scan buffer -> 2 blocks/CU -> all 512 blocks
// resident simultaneously; load/store of one block overlaps scan/compute
// of the other. (R2: 141 KB LDS, 1 block/CU, phase-serialized, 2.0 TB/s.)
//   pass1: per-thread zero-init final state d_t over its 64-sample chunk,
//          x kept in c[16] registers across the scan.
//   scan : f64 LDS Kogge-Stone over 512 chunks (verified block), P = M^64;
//          exclusive prefix s[t-1] = chunk's true entering state.
//   pass2: rerun chunk from entering state (f32), store directly.
// HBM traffic: read x once (67 MB) + write y once (67 MB). No workspace.

namespace {
constexpr int kT = 32768;
constexpr int kThreads = 512;           // 8 waves, one block per row
constexpr int kChunk = 64;              // samples per thread
}

__device__ inline void coeffs_f32(const float* g, const float* r,
                                  const float* mhp, const float* mbp,
                                  const float* mlp, float& b0, float& b1,
                                  float& b2, float& a1, float& a2) {
  float graw = g[0], rraw = r[0];
  float sig = 1.0f / (1.0f + expf(-graw));
  float gg = tanf(1.5707963267948966f * sig);            // tan(pi*sigmoid/2)
  float rr = (rraw > 20.0f) ? rraw : log1pf(expf(rraw)); // softplus
  float g2 = gg * gg;
  float m_hp = mhp[0], m_bp = mbp[0], m_lp = mlp[0];
  float B0 = g2 * m_lp + gg * m_bp + m_hp;
  float B1 = 2.0f * g2 * m_lp - 2.0f * m_hp;
  float B2 = g2 * m_lp - gg * m_bp + m_hp;
  float A0 = g2 + 2.0f * rr * gg + 1.0f;
  float A1 = 2.0f * g2 - 2.0f;
  float A2 = g2 - 2.0f * rr * gg + 1.0f;
  float inv = 1.0f / A0;
  b0 = B0 * inv; b1 = B1 * inv; b2 = B2 * inv;
  a1 = A1 * inv; a2 = A2 * inv;
}

#define IIR_STEP(xx, yy)                                         \
  do {                                                           \
    yy = fmaf(b0, xx, z1);                                       \
    z1 = fmaf(na1, yy, fmaf(b1, xx, z2));                        \
    z2 = fmaf(na2, yy, b2 * xx);                                 \
  } while (0)

#define MAT_SQ(w00, w01, w10, w11)                               \
  do {                                                           \
    double t00 = w00 * w00 + w01 * w10;                          \
    double t01 = w00 * w01 + w01 * w11;                          \
    double t10 = w10 * w00 + w11 * w10;                          \
    double t11 = w10 * w01 + w11 * w11;                          \
    w00 = t00; w01 = t01; w10 = t10; w11 = t11;                  \
  } while (0)

__global__ __launch_bounds__(kThreads, 4) void k_fused(
    const float* __restrict__ x, const float* g, const float* r,
    const float* mhp, const float* mbp, const float* mlp,
    float* __restrict__ out) {
  __shared__ double s1[kThreads], s2[kThreads];  // 8,192 B (only LDS)

  const int t = threadIdx.x;
  const size_t rowoff = (size_t)blockIdx.x * kT;

  float b0, b1, b2, a1, a2;
  coeffs_f32(g, r, mhp, mbp, mlp, b0, b1, b2, a1, a2);
  float na1 = -a1, na2 = -a2;

  // ---- load own chunk directly: 16 x dwordx4, per-thread contiguous ------
  const float4* xq = (const float4*)(x + rowoff) + t * (kChunk / 4);
  float4 c[16];
#pragma unroll
  for (int i = 0; i < 16; ++i) c[i] = xq[i];

  // ---- pass 1: zero-init chunk final state d_t ---------------------------
  float z1 = 0.f, z2 = 0.f;
#pragma unroll
  for (int i = 0; i < 16; ++i) {
    float y;
    IIR_STEP(c[i].x, y); IIR_STEP(c[i].y, y);
    IIR_STEP(c[i].z, y); IIR_STEP(c[i].w, y);
  }

  // ---- scan: f64 LDS Kogge-Stone over 512 chunks, P = M^64 ---------------
  double w00 = -(double)a1, w01 = 1.0, w10 = -(double)a2, w11 = 0.0;
#pragma unroll
  for (int i = 0; i < 6; ++i) MAT_SQ(w00, w01, w10, w11);  // P = M^64

  double A0 = (double)z1, A1 = (double)z2;
  for (int o = 1; o < kThreads; o <<= 1) {  // 9 steps
    s1[t] = A0; s2[t] = A1;
    __syncthreads();
    double q0 = 0.0, q1 = 0.0;
    if (t >= o) { q0 = s1[t - o]; q1 = s2[t - o]; }
    __syncthreads();
    A0 += w00 * q0 + w01 * q1;
    A1 += w10 * q0 + w11 * q1;
    MAT_SQ(w00, w01, w10, w11);
  }
  s1[t] = A0; s2[t] = A1;
  __syncthreads();
  double e0 = 0.0, e1 = 0.0;
  if (t > 0) { e0 = s1[t - 1]; e1 = s2[t - 1]; }  // entering state of chunk t

  // ---- pass 2: rerun chunk from true entering state, store directly ------
  z1 = (float)e0; z2 = (float)e1;
  float4* yq = (float4*)(out + rowoff) + t * (kChunk / 4);
#pragma unroll
  for (int i = 0; i < 16; ++i) {
    float4 o4;
    IIR_STEP(c[i].x, o4.x); IIR_STEP(c[i].y, o4.y);
    IIR_STEP(c[i].z, o4.z); IIR_STEP(c[i].w, o4.w);
    yq[i] = o4;
  }
}

extern "C" void kernel_launch(void* const* d_in, const int* in_sizes, int n_in,
                              void* d_out, int out_size, void* d_ws,
                              size_t ws_size, hipStream_t stream) {
  const float* x   = (const float*)d_in[0];
  const float* g   = (const float*)d_in[1];
  const float* r   = (const float*)d_in[2];
  const float* mhp = (const float*)d_in[3];
  const float* mbp = (const float*)d_in[4];
  const float* mlp = (const float*)d_in[5];
  float* out = (float*)d_out;
  (void)d_ws; (void)ws_size;

  k_fused<<<512, kThreads, 0, stream>>>(x, g, r, mhp, mbp, mlp, out);
}